// Round 13
// baseline (278.766 us; speedup 1.0000x reference)
//
#include <hip/hip_runtime.h>
#include <hip/hip_bf16.h>

typedef __attribute__((ext_vector_type(8))) short short8;
typedef __attribute__((ext_vector_type(4))) float f32x4;
typedef __attribute__((ext_vector_type(16))) float f32x16;
typedef unsigned short u16;
typedef unsigned int u32;

// B=2, T=2048, C=2048, H=16, HD=128; M = B*T = 4096, K = N = 2048
__device__ __forceinline__ u16 f2bf(float f){
  __hip_bfloat16 h = __float2bfloat16(f);
  return *reinterpret_cast<u16*>(&h);
}

__device__ __forceinline__ void gld16(const void* g, void* l){
  __builtin_amdgcn_global_load_lds((const __attribute__((address_space(1))) void*)g,
                                   (__attribute__((address_space(3))) void*)l, 16, 0, 0);
}

#define SCHED0() __builtin_amdgcn_sched_barrier(0)

// ---------------- f32 -> bf16 convert ----------------
__global__ __launch_bounds__(256) void cvt_kernel(const float* __restrict__ src,
                                                  u16* __restrict__ dst, int n){
  int i0 = (blockIdx.x*256 + threadIdx.x)*4;
  int stride = gridDim.x*256*4;
  for (int i = i0; i < n; i += stride){
    float4 f = *reinterpret_cast<const float4*>(src + i);
    ushort4 u;
    u.x = f2bf(f.x); u.y = f2bf(f.y); u.z = f2bf(f.z); u.w = f2bf(f.w);
    *reinterpret_cast<ushort4*>(dst + i) = u;
  }
}

// 4 weight matrices in one launch (blockIdx.y selects)
__global__ __launch_bounds__(256) void cvt4_kernel(
    const float* __restrict__ s0, const float* __restrict__ s1,
    const float* __restrict__ s2, const float* __restrict__ s3,
    u16* __restrict__ d0, u16* __restrict__ d1,
    u16* __restrict__ d2, u16* __restrict__ d3, int n){
  const float* s; u16* d;
  if (blockIdx.y == 0){ s = s0; d = d0; }
  else if (blockIdx.y == 1){ s = s1; d = d1; }
  else if (blockIdx.y == 2){ s = s2; d = d2; }
  else { s = s3; d = d3; }
  int i0 = (blockIdx.x*256 + threadIdx.x)*4;
  int stride = gridDim.x*256*4;
  for (int i = i0; i < n; i += stride){
    float4 f = *reinterpret_cast<const float4*>(s + i);
    ushort4 u;
    u.x = f2bf(f.x); u.y = f2bf(f.y); u.z = f2bf(f.z); u.w = f2bf(f.w);
    *reinterpret_cast<ushort4*>(d + i) = u;
  }
}

// ---------------- bf16 GEMM, 128x256 tile, BK=64, 8 waves (2Mx2Nx2K) -------
// Round-13: 32x32x16 MFMA (m119: 2495 vs 2176 TF pipe; half the MFMA insts).
// Structure otherwise = round 9 (tri-buffered LDS, counted vmcnt(6), one
// barrier per K-tile, compiler-scheduled ds_read/MFMA interleave).
// Frag layouts (verified in attn kernel): A/B lane l&31 = row/col, 16B at
// k-offset (l>>5)*8; C/D col = l&31, row = (r&3)+8*(r>>2)+4*(l>>5).
// Per wave-K-tile: af[2][2] + bf[4][2] = 12 ds_read_b128 -> 16 MFMA.
__device__ __forceinline__ void gemm256_body(const u16* __restrict__ A,
    const u16* __restrict__ W, void* __restrict__ outp, float scale, int epi)
{
  __shared__ alignas(16) u16 Lds[73728];   // 144 KiB: A 3x16KB @0, B 3x32KB @24576(u16)
  const int tid = threadIdx.x;
  const int w = tid>>6, l = tid&63;
  const int l31 = l&31, hi = l>>5;
  const int wm = w&1, wn = (w>>1)&1, wk = w>>2;   // 2M x 2N x 2K
  const int row0 = blockIdx.y*128, col0 = blockIdx.x*256;
  constexpr int K = 2048;
  constexpr int NT = K/64;

  f32x16 acc[2][4];
  #pragma unroll
  for (int i=0;i<2;i++)
    #pragma unroll
    for (int j=0;j<4;j++)
      #pragma unroll
      for (int r=0;r<16;r++) acc[i][j][r] = 0.f;

  int sBrow[4], sBcol[4];
  #pragma unroll
  for (int p=0;p<4;p++){
    int s = p*512 + tid;
    sBrow[p] = s>>3;  sBcol[p] = ((s&7) ^ ((s>>3)&7))*8;
  }
  const int sArow0 = sBrow[0], sAcol0 = sBcol[0];
  const int sArow1 = sBrow[1], sAcol1 = sBcol[1];

  auto stageA = [&](int slot, int kt){
    gld16(A + (size_t)(row0 + sArow0)*K + kt*64 + sAcol0,
          &Lds[slot*8192 + (size_t)(w*64)*8]);
    gld16(A + (size_t)(row0 + sArow1)*K + kt*64 + sAcol1,
          &Lds[slot*8192 + (size_t)(512 + w*64)*8]);
  };
  auto stageB = [&](int slot, int kt){
    #pragma unroll
    for (int p=0;p<4;p++)
      gld16(W + (size_t)(col0 + sBrow[p])*K + kt*64 + sBcol[p],
            &Lds[24576 + slot*16384 + (size_t)(p*512 + w*64)*8]);
  };
  // logical k-chunk for (kslice s, lane-half hi): ch = (wk*2+s)*2 + hi in [0,8)
  auto readA = [&](int slot, short8 (&af)[2][2]){
    #pragma unroll
    for (int i=0;i<2;i++)
      #pragma unroll
      for (int s=0;s<2;s++){
        int r = wm*64 + i*32 + l31;
        int ch = (wk*2+s)*2 + hi;
        int byt = slot*16384 + r*128 + ((ch ^ (r&7))<<4);
        af[i][s] = *reinterpret_cast<const short8*>((const char*)Lds + byt);
      }
  };
  auto readB = [&](int slot, short8 (&bf)[4][2]){
    #pragma unroll
    for (int j=0;j<4;j++)
      #pragma unroll
      for (int s=0;s<2;s++){
        int r = wn*128 + j*32 + l31;
        int ch = (wk*2+s)*2 + hi;
        int byt = 49152 + slot*32768 + r*128 + ((ch ^ (r&7))<<4);
        bf[j][s] = *reinterpret_cast<const short8*>((const char*)Lds + byt);
      }
  };

  stageA(0, 0); stageB(0, 0);
  stageA(1, 1); stageB(1, 1);
  SCHED0();
  asm volatile("s_waitcnt vmcnt(6)" ::: "memory");
  __builtin_amdgcn_s_barrier();
  SCHED0();

  int sl = 0;
  for (int t=0; t<NT; ++t){
    int st = sl+2; if (st>=3) st-=3;
    int tn = (t+2) & (NT-1);
    stageA(st, tn);
    stageB(st, tn);
    short8 af[2][2], bf[4][2];
    readA(sl, af);
    readB(sl, bf);
    #pragma unroll
    for (int i=0;i<2;i++)
      #pragma unroll
      for (int j=0;j<4;j++)
        #pragma unroll
        for (int s=0;s<2;s++)
          acc[i][j] = __builtin_amdgcn_mfma_f32_32x32x16_bf16(af[i][s], bf[j][s], acc[i][j], 0, 0, 0);
    SCHED0();
    asm volatile("s_waitcnt vmcnt(6)" ::: "memory");
    __builtin_amdgcn_s_barrier();
    SCHED0();
    sl = sl+1; if (sl>=3) sl = 0;
  }

  // ---- cross-wave K-reduce: wk=1 -> LDS -> wk=0 adds ----
  __syncthreads();
  float* R = (float*)Lds;              // 128KB as f32 (fits in 144KB)
  const int pair = wm*2 + wn;
  if (wk == 1){
    #pragma unroll
    for (int i=0;i<2;i++)
      #pragma unroll
      for (int j=0;j<4;j++)
        #pragma unroll
        for (int g=0;g<4;g++){
          f32x4 v;
          #pragma unroll
          for (int r=0;r<4;r++) v[r] = acc[i][j][g*4+r];
          *reinterpret_cast<f32x4*>(&R[pair*8192 + (i*4+j)*1024 + g*256 + l*4]) = v;
        }
  }
  __syncthreads();
  if (wk == 0){
    #pragma unroll
    for (int i=0;i<2;i++)
      #pragma unroll
      for (int j=0;j<4;j++)
        #pragma unroll
        for (int g=0;g<4;g++){
          f32x4 o = *reinterpret_cast<const f32x4*>(&R[pair*8192 + (i*4+j)*1024 + g*256 + l*4]);
          #pragma unroll
          for (int r=0;r<4;r++) acc[i][j][g*4+r] += o[r];
        }

    // epilogue: C/D col = l&31, row = (r&3)+8*(r>>2)+4*hi
    if (epi == 0){          // Q/K: bf16 scatter to [b][h][t][d]
      u16* O = (u16*)outp;
      #pragma unroll
      for (int i=0;i<2;i++)
        #pragma unroll
        for (int j=0;j<4;j++)
          #pragma unroll
          for (int r=0;r<16;r++){
            int m = row0 + wm*64 + i*32 + (r&3) + 8*(r>>2) + 4*hi;
            int n = col0 + wn*128 + j*32 + l31;
            int b = m >> 11, tt = m & 2047;
            int h = n >> 7,  d = n & 127;
            O[(((size_t)(b*16 + h)*2048 + tt)<<7) + d] = f2bf(acc[i][j][r] * scale);
          }
    } else if (epi == 2){   // V: bf16 V^T [b][h][d][t], 4 consecutive t per reg-group
      u16* O = (u16*)outp;
      #pragma unroll
      for (int i=0;i<2;i++)
        #pragma unroll
        for (int j=0;j<4;j++)
          #pragma unroll
          for (int g=0;g<4;g++){
            int m0 = row0 + wm*64 + i*32 + 8*g + 4*hi;
            int n  = col0 + wn*128 + j*32 + l31;
            int b = m0 >> 11, tt = m0 & 2047;
            int h = n >> 7,  d = n & 127;
            ushort4 u;
            u.x = f2bf(acc[i][j][g*4+0]); u.y = f2bf(acc[i][j][g*4+1]);
            u.z = f2bf(acc[i][j][g*4+2]); u.w = f2bf(acc[i][j][g*4+3]);
            *reinterpret_cast<ushort4*>(&O[(((size_t)(b*16 + h)<<7) + d)*2048 + tt]) = u;
          }
    } else {                // out-proj: f32 row-major [m][n]
      float* O = (float*)outp;
      #pragma unroll
      for (int i=0;i<2;i++)
        #pragma unroll
        for (int j=0;j<4;j++)
          #pragma unroll
          for (int r=0;r<16;r++){
            int m = row0 + wm*64 + i*32 + (r&3) + 8*(r>>2) + 4*hi;
            int n = col0 + wn*128 + j*32 + l31;
            O[(size_t)m*2048 + n] = acc[i][j][r];
          }
    }
  }
}

__global__ __launch_bounds__(512,2) void gemm_qkv(const u16* __restrict__ A,
    const u16* __restrict__ Wq, const u16* __restrict__ Wk, const u16* __restrict__ Wv,
    u16* __restrict__ qo, u16* __restrict__ ko, u16* __restrict__ vt, float qscale)
{
  const u16* W; void* O; float sc; int epi;
  if (blockIdx.z == 0){ W = Wq; O = qo; sc = qscale; epi = 0; }
  else if (blockIdx.z == 1){ W = Wk; O = ko; sc = 1.f; epi = 0; }
  else { W = Wv; O = vt; sc = 1.f; epi = 2; }
  gemm256_body(A, W, O, sc, epi);
}

__global__ __launch_bounds__(512,2) void gemm_out(const u16* __restrict__ A,
    const u16* __restrict__ W, float* __restrict__ O)
{
  gemm256_body(A, W, O, 1.f, 1);
}

// ---------------- flash attention, 32x32x16 MFMA, swapped QK^T -------------
// (unchanged from round 12 — round-5 body + setprio; best measured)
__global__ __launch_bounds__(256,2) void attn_kernel(
    const u16* __restrict__ Q, const u16* __restrict__ Kg,
    const u16* __restrict__ Vt, u16* __restrict__ Y)
{
  __shared__ alignas(16) u16 Ks[2][64*128];
  __shared__ alignas(16) u16 Vs[2][64*128];
  const int tid = threadIdx.x;
  const int w = tid>>6, l = tid&63;
  const int l31 = l&31, hi = l>>5;
  const int bh_swz = ((blockIdx.x&7)*64 + (blockIdx.x>>3));
  const int bh = bh_swz >> 4;
  const int q0 = (bh_swz & 15) * 128;

  short8 qf[8];
  #pragma unroll
  for (int ds=0; ds<8; ds++)
    qf[ds] = *reinterpret_cast<const short8*>(
        Q + ((size_t)bh*2048 + q0 + w*32 + l31)*128 + ds*16 + hi*8);

  f32x16 accO[4];
  #pragma unroll
  for (int dt=0;dt<4;dt++)
    #pragma unroll
    for (int r=0;r<16;r++) accO[dt][r] = 0.f;
  float mrun = -1e30f, lrun = 0.f;

  int krow_[4], kcol_[4], vd_[4], vkv_[4];
  #pragma unroll
  for (int p=0;p<4;p++){
    int s = p*256 + tid;
    int r = s>>4, c = s&15;
    int cu = c ^ (r&15);
    krow_[p] = r;  kcol_[p] = cu*8;
    vd_[p] = r*2 + (cu>>3);  vkv_[p] = (cu&7)*8;
  }

  auto stage = [&](int buf, int kvt){
    int kv0 = kvt*64;
    #pragma unroll
    for (int p=0;p<4;p++)
      gld16(Kg + ((size_t)bh*2048 + kv0 + krow_[p])*128 + kcol_[p],
            &Ks[buf][(size_t)(p*256 + w*64)*8]);
    #pragma unroll
    for (int p=0;p<4;p++)
      gld16(Vt + ((size_t)bh*128 + vd_[p])*2048 + kv0 + vkv_[p],
            &Vs[buf][(size_t)(p*256 + w*64)*8]);
  };

  stage(0, 0);
  __syncthreads();

  int cur = 0;
  for (int kvt=0; kvt<32; ++kvt){
    if (kvt+1 < 32) stage(cur^1, kvt+1);

    f32x16 accS[2];
    #pragma unroll
    for (int kt=0;kt<2;kt++)
      #pragma unroll
      for (int r=0;r<16;r++) accS[kt][r] = 0.f;
    __builtin_amdgcn_s_setprio(1);
    #pragma unroll
    for (int kt=0;kt<2;kt++){
      #pragma unroll
      for (int ds=0;ds<8;ds++){
        int row = kt*32 + l31;
        int byt = row*256 + (((ds*2 + hi) ^ (row&15))<<4);
        short8 kf = *reinterpret_cast<const short8*>((const char*)(&Ks[cur][0]) + byt);
        accS[kt] = __builtin_amdgcn_mfma_f32_32x32x16_bf16(kf, qf[ds], accS[kt], 0, 0, 0);
      }
    }
    __builtin_amdgcn_s_setprio(0);

    float pmax = accS[0][0];
    #pragma unroll
    for (int kt=0;kt<2;kt++)
      #pragma unroll
      for (int r=0;r<16;r++) pmax = fmaxf(pmax, accS[kt][r]);
    pmax = fmaxf(pmax, __shfl_xor(pmax, 32, 64));
    if (__any(pmax > mrun + 8.f)){
      float mn = fmaxf(mrun, pmax);
      float c = __expf(mrun - mn);
      mrun = mn;
      lrun *= c;
      #pragma unroll
      for (int r=0;r<16;r++){
        int qrow = (r&3) + 8*(r>>2) + 4*hi;
        float cr = __shfl(c, qrow, 64);
        #pragma unroll
        for (int dt=0;dt<4;dt++) accO[dt][r] *= cr;
      }
    }

    float rs = 0.f;
    short8 pa[4];
    #pragma unroll
    for (int kt=0;kt<2;kt++){
      #pragma unroll
      for (int b=0;b<2;b++){
        float e0 = __expf(accS[kt][b*8+0] - mrun);
        float e1 = __expf(accS[kt][b*8+1] - mrun);
        float e2 = __expf(accS[kt][b*8+2] - mrun);
        float e3 = __expf(accS[kt][b*8+3] - mrun);
        float e4 = __expf(accS[kt][b*8+4] - mrun);
        float e5 = __expf(accS[kt][b*8+5] - mrun);
        float e6 = __expf(accS[kt][b*8+6] - mrun);
        float e7 = __expf(accS[kt][b*8+7] - mrun);
        rs += (e0+e1)+(e2+e3)+(e4+e5)+(e6+e7);
        u32 x01 = (u32)f2bf(e0) | ((u32)f2bf(e1)<<16);
        u32 x23 = (u32)f2bf(e2) | ((u32)f2bf(e3)<<16);
        u32 y01 = (u32)f2bf(e4) | ((u32)f2bf(e5)<<16);
        u32 y23 = (u32)f2bf(e6) | ((u32)f2bf(e7)<<16);
        u32 sx_x01 = __shfl_xor(x01, 32, 64);
        u32 sx_x23 = __shfl_xor(x23, 32, 64);
        u32 sx_y01 = __shfl_xor(y01, 32, 64);
        u32 sx_y23 = __shfl_xor(y23, 32, 64);
        int4 wv;
        wv.x = (int)(hi ? sx_y01 : x01);
        wv.y = (int)(hi ? sx_y23 : x23);
        wv.z = (int)(hi ? y01 : sx_x01);
        wv.w = (int)(hi ? y23 : sx_x23);
        pa[kt*2+b] = *reinterpret_cast<short8*>(&wv);
      }
    }
    rs += __shfl_xor(rs, 32, 64);
    lrun += rs;

    __builtin_amdgcn_s_setprio(1);
    #pragma unroll
    for (int dt=0;dt<4;dt++){
      #pragma unroll
      for (int ks=0;ks<4;ks++){
        int d = dt*32 + l31;
        int cu = (d&1)*8 + ks*2 + hi;
        int byt = (d>>1)*256 + ((cu ^ ((d>>1)&15))<<4);
        short8 vf = *reinterpret_cast<const short8*>((const char*)(&Vs[cur][0]) + byt);
        accO[dt] = __builtin_amdgcn_mfma_f32_32x32x16_bf16(pa[ks], vf, accO[dt], 0, 0, 0);
      }
    }
    __builtin_amdgcn_s_setprio(0);

    __syncthreads();
    cur ^= 1;
  }

  const int b_ = bh >> 4, h_ = bh & 15;
  float inv = 1.f / lrun;
  #pragma unroll
  for (int r=0;r<16;r++){
    int qrow = (r&3) + 8*(r>>2) + 4*hi;
    float lr = __shfl(inv, qrow, 64);
    int t = q0 + w*32 + qrow;
    #pragma unroll
    for (int dt=0;dt<4;dt++){
      int d = dt*32 + l31;
      Y[((size_t)b_*2048 + t)*2048 + h_*128 + d] = f2bf(accO[dt][r] * lr);
    }
  }
}

// ---------------- launch ----------------
extern "C" void kernel_launch(void* const* d_in, const int* in_sizes, int n_in,
                              void* d_out, int out_size, void* d_ws, size_t ws_size,
                              hipStream_t stream)
{
  const float* x  = (const float*)d_in[0];
  const float* Wq = (const float*)d_in[1];
  const float* Wk = (const float*)d_in[2];
  const float* Wv = (const float*)d_in[3];
  const float* Wo = (const float*)d_in[4];
  float* out = (float*)d_out;
  char* ws = (char*)d_ws;

  const size_t MB = 1024*1024;
  u16* xb  = (u16*)(ws);            // 16 MiB bf16 x
  u16* wqb = (u16*)(ws + 16*MB);    //  8 MiB
  u16* wkb = (u16*)(ws + 24*MB);    //  8 MiB
  u16* wvb = (u16*)(ws + 32*MB);    //  8 MiB
  u16* wob = (u16*)(ws + 40*MB);    //  8 MiB
  u16* qb  = (u16*)(ws + 48*MB);    // 16 MiB [b][h][t][d]
  u16* kb  = (u16*)(ws + 64*MB);    // 16 MiB [b][h][t][d]
  u16* vtb = (u16*)(ws + 80*MB);    // 16 MiB [b][h][d][t]
  u16* yb  = wqb;                   // 16 MiB overlay: wq/wk dead after gemm_qkv

  cvt_kernel<<<2048, 256, 0, stream>>>(x, xb, 4096*2048);
  cvt4_kernel<<<dim3(1024,4), 256, 0, stream>>>(Wq, Wk, Wv, Wo,
                                                wqb, wkb, wvb, wob, 2048*2048);

  const float qscale = 0.08838834764831845f;  // 1/sqrt(128)
  gemm_qkv<<<dim3(8,32,3), 512, 0, stream>>>(xb, wqb, wkb, wvb, qb, kb, vtb, qscale);
  attn_kernel<<<512, 256, 0, stream>>>(qb, kb, vtb, yb);
  gemm_out<<<dim3(8,32), 512, 0, stream>>>(yb, wob, out);
}

// Round 14
// 274.847 us; speedup vs baseline: 1.0143x; 1.0143x over previous
//
#include <hip/hip_runtime.h>
#include <hip/hip_bf16.h>

typedef __attribute__((ext_vector_type(8))) short short8;
typedef __attribute__((ext_vector_type(4))) float f32x4;
typedef __attribute__((ext_vector_type(16))) float f32x16;
typedef unsigned short u16;
typedef unsigned int u32;

// B=2, T=2048, C=2048, H=16, HD=128; M = B*T = 4096, K = N = 2048
__device__ __forceinline__ u16 f2bf(float f){
  __hip_bfloat16 h = __float2bfloat16(f);
  return *reinterpret_cast<u16*>(&h);
}

__device__ __forceinline__ void gld16(const void* g, void* l){
  __builtin_amdgcn_global_load_lds((const __attribute__((address_space(1))) void*)g,
                                   (__attribute__((address_space(3))) void*)l, 16, 0, 0);
}

#define SCHED0() __builtin_amdgcn_sched_barrier(0)

// ---------------- f32 -> bf16 convert ----------------
__global__ __launch_bounds__(256) void cvt_kernel(const float* __restrict__ src,
                                                  u16* __restrict__ dst, int n){
  int i0 = (blockIdx.x*256 + threadIdx.x)*4;
  int stride = gridDim.x*256*4;
  for (int i = i0; i < n; i += stride){
    float4 f = *reinterpret_cast<const float4*>(src + i);
    ushort4 u;
    u.x = f2bf(f.x); u.y = f2bf(f.y); u.z = f2bf(f.z); u.w = f2bf(f.w);
    *reinterpret_cast<ushort4*>(dst + i) = u;
  }
}

// 4 weight matrices in one launch (blockIdx.y selects)
__global__ __launch_bounds__(256) void cvt4_kernel(
    const float* __restrict__ s0, const float* __restrict__ s1,
    const float* __restrict__ s2, const float* __restrict__ s3,
    u16* __restrict__ d0, u16* __restrict__ d1,
    u16* __restrict__ d2, u16* __restrict__ d3, int n){
  const float* s; u16* d;
  if (blockIdx.y == 0){ s = s0; d = d0; }
  else if (blockIdx.y == 1){ s = s1; d = d1; }
  else if (blockIdx.y == 2){ s = s2; d = d2; }
  else { s = s3; d = d3; }
  int i0 = (blockIdx.x*256 + threadIdx.x)*4;
  int stride = gridDim.x*256*4;
  for (int i = i0; i < n; i += stride){
    float4 f = *reinterpret_cast<const float4*>(s + i);
    ushort4 u;
    u.x = f2bf(f.x); u.y = f2bf(f.y); u.z = f2bf(f.z); u.w = f2bf(f.w);
    *reinterpret_cast<ushort4*>(d + i) = u;
  }
}

// ---------------- bf16 GEMM, 128x256 tile, BK=64, 8 waves (2Mx2Nx2K) -------
// Round-14: 32x32x16 MFMA + attn-proven 256B paired-row LDS layout.
// Tile rows m stored as [R=m>>1][256B]: half-row (m&1)*8+kc, 16 chunks/row,
// swizzle posP = posL ^ (R&15) — the exact layout attn's V uses, measured
// 0 bank conflicts for 32-consecutive-row ds_read_b128 (round 11/12).
// (Round-13's 128B-row ^(r&7) gave 9.4M conflicts = the 11µs regression.)
// Structure: tri-buffered LDS, counted vmcnt(6), one barrier/K-tile.
// Per wave-K-tile: af[2][2] + bf[4][2] = 12 ds_read_b128 -> 16 MFMA.
__device__ __forceinline__ void gemm256_body(const u16* __restrict__ A,
    const u16* __restrict__ W, void* __restrict__ outp, float scale, int epi)
{
  __shared__ alignas(16) u16 Lds[73728];   // 144 KiB: A 3x16KB @0, B 3x32KB @24576(u16)
  const int tid = threadIdx.x;
  const int w = tid>>6, l = tid&63;
  const int l31 = l&31, hi = l>>5;
  const int wm = w&1, wn = (w>>1)&1, wk = w>>2;   // 2M x 2N x 2K
  const int row0 = blockIdx.y*128, col0 = blockIdx.x*256;
  constexpr int K = 2048;
  constexpr int NT = K/64;

  f32x16 acc[2][4];
  #pragma unroll
  for (int i=0;i<2;i++)
    #pragma unroll
    for (int j=0;j<4;j++)
      #pragma unroll
      for (int r=0;r<16;r++) acc[i][j][r] = 0.f;

  // staging maps (paired-row layout, inverse-swizzled source, linear dest):
  // chunk c -> R = c>>4, posP = c&15, posL = posP ^ (R&15),
  //            row = 2R + (posL>>3), k-chunk = posL&7.
  int aRow[2], aK[2];      // A: chunks c = p*512 + tid, p<2 (1024 chunks)
  int bRow[4], bK[4];      // B: chunks c = p*512 + tid, p<4 (2048 chunks)
  #pragma unroll
  for (int p=0;p<4;p++){
    int c = p*512 + tid;
    int R = c>>4;
    int posL = (c&15) ^ (R&15);
    int row = R*2 + (posL>>3), kc = (posL&7)*8;
    if (p < 2){ aRow[p] = row; aK[p] = kc; }
    bRow[p] = row; bK[p] = kc;
  }

  auto stageA = [&](int slot, int kt){   // 128x64 = 16KB, 2 gld/thr
    #pragma unroll
    for (int p=0;p<2;p++)
      gld16(A + (size_t)(row0 + aRow[p])*K + kt*64 + aK[p],
            &Lds[slot*8192 + (size_t)(p*512 + w*64)*8]);
  };
  auto stageB = [&](int slot, int kt){   // 256x64 = 32KB, 4 gld/thr
    #pragma unroll
    for (int p=0;p<4;p++)
      gld16(W + (size_t)(col0 + bRow[p])*K + kt*64 + bK[p],
            &Lds[24576 + slot*16384 + (size_t)(p*512 + w*64)*8]);
  };
  // reads: row m, logical k-chunk kcL = (wk*2+s)*2 + hi; R = m>>1,
  // posP = ((m&1)*8 + kcL) ^ (R&15); byte = R*256 + posP*16.
  auto readA = [&](int slot, short8 (&af)[2][2]){
    #pragma unroll
    for (int i=0;i<2;i++)
      #pragma unroll
      for (int s=0;s<2;s++){
        int m = wm*64 + i*32 + l31;
        int kcL = (wk*2+s)*2 + hi;
        int posP = (((m&1)<<3) + kcL) ^ ((m>>1)&15);
        int byt = slot*16384 + (m>>1)*256 + (posP<<4);
        af[i][s] = *reinterpret_cast<const short8*>((const char*)Lds + byt);
      }
  };
  auto readB = [&](int slot, short8 (&bf)[4][2]){
    #pragma unroll
    for (int j=0;j<4;j++)
      #pragma unroll
      for (int s=0;s<2;s++){
        int n = wn*128 + j*32 + l31;
        int kcL = (wk*2+s)*2 + hi;
        int posP = (((n&1)<<3) + kcL) ^ ((n>>1)&15);
        int byt = 49152 + slot*32768 + (n>>1)*256 + (posP<<4);
        bf[j][s] = *reinterpret_cast<const short8*>((const char*)Lds + byt);
      }
  };

  stageA(0, 0); stageB(0, 0);
  stageA(1, 1); stageB(1, 1);
  SCHED0();
  asm volatile("s_waitcnt vmcnt(6)" ::: "memory");
  __builtin_amdgcn_s_barrier();
  SCHED0();

  int sl = 0;
  for (int t=0; t<NT; ++t){
    int st = sl+2; if (st>=3) st-=3;
    int tn = (t+2) & (NT-1);
    stageA(st, tn);
    stageB(st, tn);
    short8 af[2][2], bf[4][2];
    readA(sl, af);
    readB(sl, bf);
    #pragma unroll
    for (int i=0;i<2;i++)
      #pragma unroll
      for (int j=0;j<4;j++)
        #pragma unroll
        for (int s=0;s<2;s++)
          acc[i][j] = __builtin_amdgcn_mfma_f32_32x32x16_bf16(af[i][s], bf[j][s], acc[i][j], 0, 0, 0);
    SCHED0();
    asm volatile("s_waitcnt vmcnt(6)" ::: "memory");
    __builtin_amdgcn_s_barrier();
    SCHED0();
    sl = sl+1; if (sl>=3) sl = 0;
  }

  // ---- cross-wave K-reduce: wk=1 -> LDS -> wk=0 adds ----
  __syncthreads();
  float* R = (float*)Lds;              // 128KB as f32 (fits in 144KB)
  const int pair = wm*2 + wn;
  if (wk == 1){
    #pragma unroll
    for (int i=0;i<2;i++)
      #pragma unroll
      for (int j=0;j<4;j++)
        #pragma unroll
        for (int g=0;g<4;g++){
          f32x4 v;
          #pragma unroll
          for (int r=0;r<4;r++) v[r] = acc[i][j][g*4+r];
          *reinterpret_cast<f32x4*>(&R[pair*8192 + (i*4+j)*1024 + g*256 + l*4]) = v;
        }
  }
  __syncthreads();
  if (wk == 0){
    #pragma unroll
    for (int i=0;i<2;i++)
      #pragma unroll
      for (int j=0;j<4;j++)
        #pragma unroll
        for (int g=0;g<4;g++){
          f32x4 o = *reinterpret_cast<const f32x4*>(&R[pair*8192 + (i*4+j)*1024 + g*256 + l*4]);
          #pragma unroll
          for (int r=0;r<4;r++) acc[i][j][g*4+r] += o[r];
        }

    // epilogue: C/D col = l&31, row = (r&3)+8*(r>>2)+4*hi  (validated r13)
    if (epi == 0){          // Q/K: bf16 scatter to [b][h][t][d]
      u16* O = (u16*)outp;
      #pragma unroll
      for (int i=0;i<2;i++)
        #pragma unroll
        for (int j=0;j<4;j++)
          #pragma unroll
          for (int r=0;r<16;r++){
            int m = row0 + wm*64 + i*32 + (r&3) + 8*(r>>2) + 4*hi;
            int n = col0 + wn*128 + j*32 + l31;
            int b = m >> 11, tt = m & 2047;
            int h = n >> 7,  d = n & 127;
            O[(((size_t)(b*16 + h)*2048 + tt)<<7) + d] = f2bf(acc[i][j][r] * scale);
          }
    } else if (epi == 2){   // V: bf16 V^T [b][h][d][t], 4 consecutive t per reg-group
      u16* O = (u16*)outp;
      #pragma unroll
      for (int i=0;i<2;i++)
        #pragma unroll
        for (int j=0;j<4;j++)
          #pragma unroll
          for (int g=0;g<4;g++){
            int m0 = row0 + wm*64 + i*32 + 8*g + 4*hi;
            int n  = col0 + wn*128 + j*32 + l31;
            int b = m0 >> 11, tt = m0 & 2047;
            int h = n >> 7,  d = n & 127;
            ushort4 u;
            u.x = f2bf(acc[i][j][g*4+0]); u.y = f2bf(acc[i][j][g*4+1]);
            u.z = f2bf(acc[i][j][g*4+2]); u.w = f2bf(acc[i][j][g*4+3]);
            *reinterpret_cast<ushort4*>(&O[(((size_t)(b*16 + h)<<7) + d)*2048 + tt]) = u;
          }
    } else {                // out-proj: f32 row-major [m][n]
      float* O = (float*)outp;
      #pragma unroll
      for (int i=0;i<2;i++)
        #pragma unroll
        for (int j=0;j<4;j++)
          #pragma unroll
          for (int r=0;r<16;r++){
            int m = row0 + wm*64 + i*32 + (r&3) + 8*(r>>2) + 4*hi;
            int n = col0 + wn*128 + j*32 + l31;
            O[(size_t)m*2048 + n] = acc[i][j][r];
          }
    }
  }
}

__global__ __launch_bounds__(512,2) void gemm_qkv(const u16* __restrict__ A,
    const u16* __restrict__ Wq, const u16* __restrict__ Wk, const u16* __restrict__ Wv,
    u16* __restrict__ qo, u16* __restrict__ ko, u16* __restrict__ vt, float qscale)
{
  const u16* W; void* O; float sc; int epi;
  if (blockIdx.z == 0){ W = Wq; O = qo; sc = qscale; epi = 0; }
  else if (blockIdx.z == 1){ W = Wk; O = ko; sc = 1.f; epi = 0; }
  else { W = Wv; O = vt; sc = 1.f; epi = 2; }
  gemm256_body(A, W, O, sc, epi);
}

__global__ __launch_bounds__(512,2) void gemm_out(const u16* __restrict__ A,
    const u16* __restrict__ W, float* __restrict__ O)
{
  gemm256_body(A, W, O, 1.f, 1);
}

// ---------------- flash attention, 32x32x16 MFMA, swapped QK^T -------------
// (unchanged from round 12 — best measured)
__global__ __launch_bounds__(256,2) void attn_kernel(
    const u16* __restrict__ Q, const u16* __restrict__ Kg,
    const u16* __restrict__ Vt, u16* __restrict__ Y)
{
  __shared__ alignas(16) u16 Ks[2][64*128];
  __shared__ alignas(16) u16 Vs[2][64*128];
  const int tid = threadIdx.x;
  const int w = tid>>6, l = tid&63;
  const int l31 = l&31, hi = l>>5;
  const int bh_swz = ((blockIdx.x&7)*64 + (blockIdx.x>>3));
  const int bh = bh_swz >> 4;
  const int q0 = (bh_swz & 15) * 128;

  short8 qf[8];
  #pragma unroll
  for (int ds=0; ds<8; ds++)
    qf[ds] = *reinterpret_cast<const short8*>(
        Q + ((size_t)bh*2048 + q0 + w*32 + l31)*128 + ds*16 + hi*8);

  f32x16 accO[4];
  #pragma unroll
  for (int dt=0;dt<4;dt++)
    #pragma unroll
    for (int r=0;r<16;r++) accO[dt][r] = 0.f;
  float mrun = -1e30f, lrun = 0.f;

  int krow_[4], kcol_[4], vd_[4], vkv_[4];
  #pragma unroll
  for (int p=0;p<4;p++){
    int s = p*256 + tid;
    int r = s>>4, c = s&15;
    int cu = c ^ (r&15);
    krow_[p] = r;  kcol_[p] = cu*8;
    vd_[p] = r*2 + (cu>>3);  vkv_[p] = (cu&7)*8;
  }

  auto stage = [&](int buf, int kvt){
    int kv0 = kvt*64;
    #pragma unroll
    for (int p=0;p<4;p++)
      gld16(Kg + ((size_t)bh*2048 + kv0 + krow_[p])*128 + kcol_[p],
            &Ks[buf][(size_t)(p*256 + w*64)*8]);
    #pragma unroll
    for (int p=0;p<4;p++)
      gld16(Vt + ((size_t)bh*128 + vd_[p])*2048 + kv0 + vkv_[p],
            &Vs[buf][(size_t)(p*256 + w*64)*8]);
  };

  stage(0, 0);
  __syncthreads();

  int cur = 0;
  for (int kvt=0; kvt<32; ++kvt){
    if (kvt+1 < 32) stage(cur^1, kvt+1);

    f32x16 accS[2];
    #pragma unroll
    for (int kt=0;kt<2;kt++)
      #pragma unroll
      for (int r=0;r<16;r++) accS[kt][r] = 0.f;
    __builtin_amdgcn_s_setprio(1);
    #pragma unroll
    for (int kt=0;kt<2;kt++){
      #pragma unroll
      for (int ds=0;ds<8;ds++){
        int row = kt*32 + l31;
        int byt = row*256 + (((ds*2 + hi) ^ (row&15))<<4);
        short8 kf = *reinterpret_cast<const short8*>((const char*)(&Ks[cur][0]) + byt);
        accS[kt] = __builtin_amdgcn_mfma_f32_32x32x16_bf16(kf, qf[ds], accS[kt], 0, 0, 0);
      }
    }
    __builtin_amdgcn_s_setprio(0);

    float pmax = accS[0][0];
    #pragma unroll
    for (int kt=0;kt<2;kt++)
      #pragma unroll
      for (int r=0;r<16;r++) pmax = fmaxf(pmax, accS[kt][r]);
    pmax = fmaxf(pmax, __shfl_xor(pmax, 32, 64));
    if (__any(pmax > mrun + 8.f)){
      float mn = fmaxf(mrun, pmax);
      float c = __expf(mrun - mn);
      mrun = mn;
      lrun *= c;
      #pragma unroll
      for (int r=0;r<16;r++){
        int qrow = (r&3) + 8*(r>>2) + 4*hi;
        float cr = __shfl(c, qrow, 64);
        #pragma unroll
        for (int dt=0;dt<4;dt++) accO[dt][r] *= cr;
      }
    }

    float rs = 0.f;
    short8 pa[4];
    #pragma unroll
    for (int kt=0;kt<2;kt++){
      #pragma unroll
      for (int b=0;b<2;b++){
        float e0 = __expf(accS[kt][b*8+0] - mrun);
        float e1 = __expf(accS[kt][b*8+1] - mrun);
        float e2 = __expf(accS[kt][b*8+2] - mrun);
        float e3 = __expf(accS[kt][b*8+3] - mrun);
        float e4 = __expf(accS[kt][b*8+4] - mrun);
        float e5 = __expf(accS[kt][b*8+5] - mrun);
        float e6 = __expf(accS[kt][b*8+6] - mrun);
        float e7 = __expf(accS[kt][b*8+7] - mrun);
        rs += (e0+e1)+(e2+e3)+(e4+e5)+(e6+e7);
        u32 x01 = (u32)f2bf(e0) | ((u32)f2bf(e1)<<16);
        u32 x23 = (u32)f2bf(e2) | ((u32)f2bf(e3)<<16);
        u32 y01 = (u32)f2bf(e4) | ((u32)f2bf(e5)<<16);
        u32 y23 = (u32)f2bf(e6) | ((u32)f2bf(e7)<<16);
        u32 sx_x01 = __shfl_xor(x01, 32, 64);
        u32 sx_x23 = __shfl_xor(x23, 32, 64);
        u32 sx_y01 = __shfl_xor(y01, 32, 64);
        u32 sx_y23 = __shfl_xor(y23, 32, 64);
        int4 wv;
        wv.x = (int)(hi ? sx_y01 : x01);
        wv.y = (int)(hi ? sx_y23 : x23);
        wv.z = (int)(hi ? y01 : sx_x01);
        wv.w = (int)(hi ? y23 : sx_x23);
        pa[kt*2+b] = *reinterpret_cast<short8*>(&wv);
      }
    }
    rs += __shfl_xor(rs, 32, 64);
    lrun += rs;

    __builtin_amdgcn_s_setprio(1);
    #pragma unroll
    for (int dt=0;dt<4;dt++){
      #pragma unroll
      for (int ks=0;ks<4;ks++){
        int d = dt*32 + l31;
        int cu = (d&1)*8 + ks*2 + hi;
        int byt = (d>>1)*256 + ((cu ^ ((d>>1)&15))<<4);
        short8 vf = *reinterpret_cast<const short8*>((const char*)(&Vs[cur][0]) + byt);
        accO[dt] = __builtin_amdgcn_mfma_f32_32x32x16_bf16(pa[ks], vf, accO[dt], 0, 0, 0);
      }
    }
    __builtin_amdgcn_s_setprio(0);

    __syncthreads();
    cur ^= 1;
  }

  const int b_ = bh >> 4, h_ = bh & 15;
  float inv = 1.f / lrun;
  #pragma unroll
  for (int r=0;r<16;r++){
    int qrow = (r&3) + 8*(r>>2) + 4*hi;
    float lr = __shfl(inv, qrow, 64);
    int t = q0 + w*32 + qrow;
    #pragma unroll
    for (int dt=0;dt<4;dt++){
      int d = dt*32 + l31;
      Y[((size_t)b_*2048 + t)*2048 + h_*128 + d] = f2bf(accO[dt][r] * lr);
    }
  }
}

// ---------------- launch ----------------
extern "C" void kernel_launch(void* const* d_in, const int* in_sizes, int n_in,
                              void* d_out, int out_size, void* d_ws, size_t ws_size,
                              hipStream_t stream)
{
  const float* x  = (const float*)d_in[0];
  const float* Wq = (const float*)d_in[1];
  const float* Wk = (const float*)d_in[2];
  const float* Wv = (const float*)d_in[3];
  const float* Wo = (const float*)d_in[4];
  float* out = (float*)d_out;
  char* ws = (char*)d_ws;

  const size_t MB = 1024*1024;
  u16* xb  = (u16*)(ws);            // 16 MiB bf16 x
  u16* wqb = (u16*)(ws + 16*MB);    //  8 MiB
  u16* wkb = (u16*)(ws + 24*MB);    //  8 MiB
  u16* wvb = (u16*)(ws + 32*MB);    //  8 MiB
  u16* wob = (u16*)(ws + 40*MB);    //  8 MiB
  u16* qb  = (u16*)(ws + 48*MB);    // 16 MiB [b][h][t][d]
  u16* kb  = (u16*)(ws + 64*MB);    // 16 MiB [b][h][t][d]
  u16* vtb = (u16*)(ws + 80*MB);    // 16 MiB [b][h][d][t]
  u16* yb  = wqb;                   // 16 MiB overlay: wq/wk dead after gemm_qkv

  cvt_kernel<<<2048, 256, 0, stream>>>(x, xb, 4096*2048);
  cvt4_kernel<<<dim3(1024,4), 256, 0, stream>>>(Wq, Wk, Wv, Wo,
                                                wqb, wkb, wvb, wob, 2048*2048);

  const float qscale = 0.08838834764831845f;  // 1/sqrt(128)
  gemm_qkv<<<dim3(8,32,3), 512, 0, stream>>>(xb, wqb, wkb, wvb, qb, kb, vtb, qscale);
  attn_kernel<<<512, 256, 0, stream>>>(qb, kb, vtb, yb);
  gemm_out<<<dim3(8,32), 512, 0, stream>>>(yb, wob, out);
}

// Round 15
// 258.809 us; speedup vs baseline: 1.0771x; 1.0620x over previous
//
#include <hip/hip_runtime.h>
#include <hip/hip_bf16.h>

typedef __attribute__((ext_vector_type(8))) short short8;
typedef __attribute__((ext_vector_type(4))) float f32x4;
typedef __attribute__((ext_vector_type(16))) float f32x16;
typedef unsigned short u16;
typedef unsigned int u32;

// B=2, T=2048, C=2048, H=16, HD=128; M = B*T = 4096, K = N = 2048
__device__ __forceinline__ u16 f2bf(float f){
  __hip_bfloat16 h = __float2bfloat16(f);
  return *reinterpret_cast<u16*>(&h);
}

__device__ __forceinline__ void gld16(const void* g, void* l){
  __builtin_amdgcn_global_load_lds((const __attribute__((address_space(1))) void*)g,
                                   (__attribute__((address_space(3))) void*)l, 16, 0, 0);
}

#define SCHED0() __builtin_amdgcn_sched_barrier(0)

// ---------------- f32 -> bf16 convert: ALL tensors in one launch ----------
// grid (1024, 6): y=0,1 -> x halves (4M elems each); y=2..5 -> Wq,Wk,Wv,Wo.
__global__ __launch_bounds__(256) void cvt_all(
    const float* __restrict__ x,
    const float* __restrict__ w0, const float* __restrict__ w1,
    const float* __restrict__ w2, const float* __restrict__ w3,
    u16* __restrict__ xb,
    u16* __restrict__ d0, u16* __restrict__ d1,
    u16* __restrict__ d2, u16* __restrict__ d3){
  const float* s; u16* d;
  const int y = blockIdx.y;
  if (y == 0){ s = x;            d = xb; }
  else if (y == 1){ s = x + 4194304; d = xb + 4194304; }
  else if (y == 2){ s = w0; d = d0; }
  else if (y == 3){ s = w1; d = d1; }
  else if (y == 4){ s = w2; d = d2; }
  else { s = w3; d = d3; }
  const int n = 4194304;
  int i0 = (blockIdx.x*256 + threadIdx.x)*4;
  int stride = gridDim.x*256*4;
  for (int i = i0; i < n; i += stride){
    float4 f = *reinterpret_cast<const float4*>(s + i);
    ushort4 u;
    u.x = f2bf(f.x); u.y = f2bf(f.y); u.z = f2bf(f.z); u.w = f2bf(f.w);
    *reinterpret_cast<ushort4*>(d + i) = u;
  }
}

// ---------------- bf16 GEMM, 128x256 tile, BK=64, 8 waves (2Mx2Nx2K) -------
// (frozen round-9 structure — best measured: ~117µs qkv, 0 conflicts)
__device__ __forceinline__ void gemm256_body(const u16* __restrict__ A,
    const u16* __restrict__ W, void* __restrict__ outp, float scale, int epi)
{
  __shared__ alignas(16) u16 Lds[73728];   // 144 KiB
  const int tid = threadIdx.x;
  const int w = tid>>6, l = tid&63;
  const int l15 = l&15, lg = l>>4;
  const int wm = w&1, wn = (w>>1)&1, wk = w>>2;   // 2M x 2N x 2K
  const int row0 = blockIdx.y*128, col0 = blockIdx.x*256;
  constexpr int K = 2048;
  constexpr int NT = K/64;

  f32x4 acc[4][8];
  #pragma unroll
  for (int i=0;i<4;i++)
    #pragma unroll
    for (int j=0;j<8;j++)
      #pragma unroll
      for (int r=0;r<4;r++) acc[i][j][r] = 0.f;

  int sBrow[4], sBcol[4];
  #pragma unroll
  for (int p=0;p<4;p++){
    int s = p*512 + tid;
    sBrow[p] = s>>3;  sBcol[p] = ((s&7) ^ ((s>>3)&7))*8;
  }
  const int sArow0 = sBrow[0], sAcol0 = sBcol[0];
  const int sArow1 = sBrow[1], sAcol1 = sBcol[1];

  auto stageA = [&](int slot, int kt){
    gld16(A + (size_t)(row0 + sArow0)*K + kt*64 + sAcol0,
          &Lds[slot*8192 + (size_t)(w*64)*8]);
    gld16(A + (size_t)(row0 + sArow1)*K + kt*64 + sAcol1,
          &Lds[slot*8192 + (size_t)(512 + w*64)*8]);
  };
  auto stageB = [&](int slot, int kt){
    #pragma unroll
    for (int p=0;p<4;p++)
      gld16(W + (size_t)(col0 + sBrow[p])*K + kt*64 + sBcol[p],
            &Lds[24576 + slot*16384 + (size_t)(p*512 + w*64)*8]);
  };
  auto readA = [&](int slot, short8 (&af)[4]){
    #pragma unroll
    for (int i=0;i<4;i++){
      int r = wm*64 + i*16 + l15;
      int byt = slot*16384 + r*128 + (((wk*4+lg) ^ (r&7))<<4);
      af[i] = *reinterpret_cast<const short8*>((const char*)Lds + byt);
    }
  };
  auto readB = [&](int slot, short8 (&bf)[8]){
    #pragma unroll
    for (int j=0;j<8;j++){
      int r = wn*128 + j*16 + l15;
      int byt = 49152 + slot*32768 + r*128 + (((wk*4+lg) ^ (r&7))<<4);
      bf[j] = *reinterpret_cast<const short8*>((const char*)Lds + byt);
    }
  };

  stageA(0, 0); stageB(0, 0);
  stageA(1, 1); stageB(1, 1);
  SCHED0();
  asm volatile("s_waitcnt vmcnt(6)" ::: "memory");
  __builtin_amdgcn_s_barrier();
  SCHED0();

  int sl = 0;
  for (int t=0; t<NT; ++t){
    int st = sl+2; if (st>=3) st-=3;
    int tn = (t+2) & (NT-1);
    stageA(st, tn);
    stageB(st, tn);
    short8 af[4], bf[8];
    readA(sl, af);
    readB(sl, bf);
    #pragma unroll
    for (int i=0;i<4;i++)
      #pragma unroll
      for (int j=0;j<8;j++)
        acc[i][j] = __builtin_amdgcn_mfma_f32_16x16x32_bf16(af[i], bf[j], acc[i][j], 0, 0, 0);
    SCHED0();
    asm volatile("s_waitcnt vmcnt(6)" ::: "memory");
    __builtin_amdgcn_s_barrier();
    SCHED0();
    sl = sl+1; if (sl>=3) sl = 0;
  }

  __syncthreads();
  float* R = (float*)Lds;
  const int pair = wm*2 + wn;
  if (wk == 1){
    #pragma unroll
    for (int i=0;i<4;i++)
      #pragma unroll
      for (int j=0;j<8;j++)
        *reinterpret_cast<f32x4*>(&R[pair*8192 + (i*8+j)*256 + l*4]) = acc[i][j];
  }
  __syncthreads();
  if (wk == 0){
    #pragma unroll
    for (int i=0;i<4;i++)
      #pragma unroll
      for (int j=0;j<8;j++){
        f32x4 o = *reinterpret_cast<const f32x4*>(&R[pair*8192 + (i*8+j)*256 + l*4]);
        #pragma unroll
        for (int r=0;r<4;r++) acc[i][j][r] += o[r];
      }

    if (epi == 0){          // Q/K: bf16 scatter to [b][h][t][d]
      u16* O = (u16*)outp;
      #pragma unroll
      for (int i=0;i<4;i++)
        #pragma unroll
        for (int j=0;j<8;j++)
          #pragma unroll
          for (int r=0;r<4;r++){
            int m = row0 + wm*64 + i*16 + lg*4 + r;
            int n = col0 + wn*128 + j*16 + l15;
            int b = m >> 11, tt = m & 2047;
            int h = n >> 7,  d = n & 127;
            O[(((size_t)(b*16 + h)*2048 + tt)<<7) + d] = f2bf(acc[i][j][r] * scale);
          }
    } else if (epi == 2){   // V: bf16 V^T [b][h][d][t]
      u16* O = (u16*)outp;
      #pragma unroll
      for (int i=0;i<4;i++)
        #pragma unroll
        for (int j=0;j<8;j++){
          int m0 = row0 + wm*64 + i*16 + lg*4;
          int n  = col0 + wn*128 + j*16 + l15;
          int b = m0 >> 11, tt = m0 & 2047;
          int h = n >> 7,  d = n & 127;
          ushort4 u;
          u.x = f2bf(acc[i][j][0]); u.y = f2bf(acc[i][j][1]);
          u.z = f2bf(acc[i][j][2]); u.w = f2bf(acc[i][j][3]);
          *reinterpret_cast<ushort4*>(&O[(((size_t)(b*16 + h)<<7) + d)*2048 + tt]) = u;
        }
    } else {                // out-proj: f32 row-major [m][n]
      float* O = (float*)outp;
      #pragma unroll
      for (int i=0;i<4;i++)
        #pragma unroll
        for (int j=0;j<8;j++)
          #pragma unroll
          for (int r=0;r<4;r++){
            int m = row0 + wm*64 + i*16 + lg*4 + r;
            int n = col0 + wn*128 + j*16 + l15;
            O[(size_t)m*2048 + n] = acc[i][j][r];
          }
    }
  }
}

__global__ __launch_bounds__(512,2) void gemm_qkv(const u16* __restrict__ A,
    const u16* __restrict__ Wq, const u16* __restrict__ Wk, const u16* __restrict__ Wv,
    u16* __restrict__ qo, u16* __restrict__ ko, u16* __restrict__ vt, float qscale)
{
  const u16* W; void* O; float sc; int epi;
  if (blockIdx.z == 0){ W = Wq; O = qo; sc = qscale; epi = 0; }
  else if (blockIdx.z == 1){ W = Wk; O = ko; sc = 1.f; epi = 0; }
  else { W = Wv; O = vt; sc = 1.f; epi = 2; }
  gemm256_body(A, W, O, sc, epi);
}

__global__ __launch_bounds__(512,2) void gemm_out(const u16* __restrict__ A,
    const u16* __restrict__ W, float* __restrict__ O)
{
  gemm256_body(A, W, O, 1.f, 1);
}

// ---------------- flash attention, 32x32x16 MFMA, swapped QK^T -------------
// (frozen round-12 — best measured)
__global__ __launch_bounds__(256,2) void attn_kernel(
    const u16* __restrict__ Q, const u16* __restrict__ Kg,
    const u16* __restrict__ Vt, u16* __restrict__ Y)
{
  __shared__ alignas(16) u16 Ks[2][64*128];
  __shared__ alignas(16) u16 Vs[2][64*128];
  const int tid = threadIdx.x;
  const int w = tid>>6, l = tid&63;
  const int l31 = l&31, hi = l>>5;
  const int bh_swz = ((blockIdx.x&7)*64 + (blockIdx.x>>3));
  const int bh = bh_swz >> 4;
  const int q0 = (bh_swz & 15) * 128;

  short8 qf[8];
  #pragma unroll
  for (int ds=0; ds<8; ds++)
    qf[ds] = *reinterpret_cast<const short8*>(
        Q + ((size_t)bh*2048 + q0 + w*32 + l31)*128 + ds*16 + hi*8);

  f32x16 accO[4];
  #pragma unroll
  for (int dt=0;dt<4;dt++)
    #pragma unroll
    for (int r=0;r<16;r++) accO[dt][r] = 0.f;
  float mrun = -1e30f, lrun = 0.f;

  int krow_[4], kcol_[4], vd_[4], vkv_[4];
  #pragma unroll
  for (int p=0;p<4;p++){
    int s = p*256 + tid;
    int r = s>>4, c = s&15;
    int cu = c ^ (r&15);
    krow_[p] = r;  kcol_[p] = cu*8;
    vd_[p] = r*2 + (cu>>3);  vkv_[p] = (cu&7)*8;
  }

  auto stage = [&](int buf, int kvt){
    int kv0 = kvt*64;
    #pragma unroll
    for (int p=0;p<4;p++)
      gld16(Kg + ((size_t)bh*2048 + kv0 + krow_[p])*128 + kcol_[p],
            &Ks[buf][(size_t)(p*256 + w*64)*8]);
    #pragma unroll
    for (int p=0;p<4;p++)
      gld16(Vt + ((size_t)bh*128 + vd_[p])*2048 + kv0 + vkv_[p],
            &Vs[buf][(size_t)(p*256 + w*64)*8]);
  };

  stage(0, 0);
  __syncthreads();

  int cur = 0;
  for (int kvt=0; kvt<32; ++kvt){
    if (kvt+1 < 32) stage(cur^1, kvt+1);

    f32x16 accS[2];
    #pragma unroll
    for (int kt=0;kt<2;kt++)
      #pragma unroll
      for (int r=0;r<16;r++) accS[kt][r] = 0.f;
    __builtin_amdgcn_s_setprio(1);
    #pragma unroll
    for (int kt=0;kt<2;kt++){
      #pragma unroll
      for (int ds=0;ds<8;ds++){
        int row = kt*32 + l31;
        int byt = row*256 + (((ds*2 + hi) ^ (row&15))<<4);
        short8 kf = *reinterpret_cast<const short8*>((const char*)(&Ks[cur][0]) + byt);
        accS[kt] = __builtin_amdgcn_mfma_f32_32x32x16_bf16(kf, qf[ds], accS[kt], 0, 0, 0);
      }
    }
    __builtin_amdgcn_s_setprio(0);

    float pmax = accS[0][0];
    #pragma unroll
    for (int kt=0;kt<2;kt++)
      #pragma unroll
      for (int r=0;r<16;r++) pmax = fmaxf(pmax, accS[kt][r]);
    pmax = fmaxf(pmax, __shfl_xor(pmax, 32, 64));
    if (__any(pmax > mrun + 8.f)){
      float mn = fmaxf(mrun, pmax);
      float c = __expf(mrun - mn);
      mrun = mn;
      lrun *= c;
      #pragma unroll
      for (int r=0;r<16;r++){
        int qrow = (r&3) + 8*(r>>2) + 4*hi;
        float cr = __shfl(c, qrow, 64);
        #pragma unroll
        for (int dt=0;dt<4;dt++) accO[dt][r] *= cr;
      }
    }

    float rs = 0.f;
    short8 pa[4];
    #pragma unroll
    for (int kt=0;kt<2;kt++){
      #pragma unroll
      for (int b=0;b<2;b++){
        float e0 = __expf(accS[kt][b*8+0] - mrun);
        float e1 = __expf(accS[kt][b*8+1] - mrun);
        float e2 = __expf(accS[kt][b*8+2] - mrun);
        float e3 = __expf(accS[kt][b*8+3] - mrun);
        float e4 = __expf(accS[kt][b*8+4] - mrun);
        float e5 = __expf(accS[kt][b*8+5] - mrun);
        float e6 = __expf(accS[kt][b*8+6] - mrun);
        float e7 = __expf(accS[kt][b*8+7] - mrun);
        rs += (e0+e1)+(e2+e3)+(e4+e5)+(e6+e7);
        u32 x01 = (u32)f2bf(e0) | ((u32)f2bf(e1)<<16);
        u32 x23 = (u32)f2bf(e2) | ((u32)f2bf(e3)<<16);
        u32 y01 = (u32)f2bf(e4) | ((u32)f2bf(e5)<<16);
        u32 y23 = (u32)f2bf(e6) | ((u32)f2bf(e7)<<16);
        u32 sx_x01 = __shfl_xor(x01, 32, 64);
        u32 sx_x23 = __shfl_xor(x23, 32, 64);
        u32 sx_y01 = __shfl_xor(y01, 32, 64);
        u32 sx_y23 = __shfl_xor(y23, 32, 64);
        int4 wv;
        wv.x = (int)(hi ? sx_y01 : x01);
        wv.y = (int)(hi ? sx_y23 : x23);
        wv.z = (int)(hi ? y01 : sx_x01);
        wv.w = (int)(hi ? y23 : sx_x23);
        pa[kt*2+b] = *reinterpret_cast<short8*>(&wv);
      }
    }
    rs += __shfl_xor(rs, 32, 64);
    lrun += rs;

    __builtin_amdgcn_s_setprio(1);
    #pragma unroll
    for (int dt=0;dt<4;dt++){
      #pragma unroll
      for (int ks=0;ks<4;ks++){
        int d = dt*32 + l31;
        int cu = (d&1)*8 + ks*2 + hi;
        int byt = (d>>1)*256 + ((cu ^ ((d>>1)&15))<<4);
        short8 vf = *reinterpret_cast<const short8*>((const char*)(&Vs[cur][0]) + byt);
        accO[dt] = __builtin_amdgcn_mfma_f32_32x32x16_bf16(pa[ks], vf, accO[dt], 0, 0, 0);
      }
    }
    __builtin_amdgcn_s_setprio(0);

    __syncthreads();
    cur ^= 1;
  }

  const int b_ = bh >> 4, h_ = bh & 15;
  float inv = 1.f / lrun;
  #pragma unroll
  for (int r=0;r<16;r++){
    int qrow = (r&3) + 8*(r>>2) + 4*hi;
    float lr = __shfl(inv, qrow, 64);
    int t = q0 + w*32 + qrow;
    #pragma unroll
    for (int dt=0;dt<4;dt++){
      int d = dt*32 + l31;
      Y[((size_t)b_*2048 + t)*2048 + h_*128 + d] = f2bf(accO[dt][r] * lr);
    }
  }
}

// ---------------- launch ----------------
extern "C" void kernel_launch(void* const* d_in, const int* in_sizes, int n_in,
                              void* d_out, int out_size, void* d_ws, size_t ws_size,
                              hipStream_t stream)
{
  const float* x  = (const float*)d_in[0];
  const float* Wq = (const float*)d_in[1];
  const float* Wk = (const float*)d_in[2];
  const float* Wv = (const float*)d_in[3];
  const float* Wo = (const float*)d_in[4];
  float* out = (float*)d_out;
  char* ws = (char*)d_ws;

  const size_t MB = 1024*1024;
  u16* xb  = (u16*)(ws);            // 16 MiB bf16 x
  u16* wqb = (u16*)(ws + 16*MB);    //  8 MiB
  u16* wkb = (u16*)(ws + 24*MB);    //  8 MiB
  u16* wvb = (u16*)(ws + 32*MB);    //  8 MiB
  u16* wob = (u16*)(ws + 40*MB);    //  8 MiB
  u16* qb  = (u16*)(ws + 48*MB);    // 16 MiB [b][h][t][d]
  u16* kb  = (u16*)(ws + 64*MB);    // 16 MiB [b][h][t][d]
  u16* vtb = (u16*)(ws + 80*MB);    // 16 MiB [b][h][d][t]
  u16* yb  = wqb;                   // 16 MiB overlay: wq/wk dead after gemm_qkv

  cvt_all<<<dim3(1024,6), 256, 0, stream>>>(x, Wq, Wk, Wv, Wo,
                                            xb, wqb, wkb, wvb, wob);

  const float qscale = 0.08838834764831845f;  // 1/sqrt(128)
  gemm_qkv<<<dim3(8,32,3), 512, 0, stream>>>(xb, wqb, wkb, wvb, qb, kb, vtb, qscale);
  attn_kernel<<<512, 256, 0, stream>>>(qb, kb, vtb, yb);
  gemm_out<<<dim3(8,32), 512, 0, stream>>>(yb, wob, out);
}